// Round 1
// baseline (299.990 us; speedup 1.0000x reference)
//
#include <hip/hip_runtime.h>
#include <math.h>

#define T 20
#define MAXA 9408

__device__ __forceinline__ unsigned mapf(float x) {
    unsigned u = __float_as_uint(x);
    return (u & 0x80000000u) ? ~u : (u | 0x80000000u);
}
__device__ __forceinline__ float unmapf(unsigned m) {
    return __uint_as_float((m & 0x80000000u) ? (m ^ 0x80000000u) : ~m);
}
// bce(x, y=1) = max(x,0) - x + log1p(exp(-|x|))
__device__ __forceinline__ float bce_pos(float x) {
    return fmaxf(x, 0.f) - x + log1pf(expf(-fabsf(x)));
}
// bce(x, y=0) = max(x,0) + log1p(exp(-|x|))
__device__ __forceinline__ float bce_neg(float x) {
    return fmaxf(x, 0.f) + log1pf(expf(-fabsf(x)));
}

__global__ __launch_bounds__(256) void det_loss_kernel(
    const float* __restrict__ pred1, const float* __restrict__ pred2,
    const float* __restrict__ pred3,
    const float* __restrict__ anc1, const float* __restrict__ anc2,
    const float* __restrict__ anc3,
    const float* __restrict__ tboxes, const int* __restrict__ tlabels,
    float* __restrict__ acc)
{
    const int bid = blockIdx.x;
    const int b = bid / 3;
    const int s = bid % 3;
    const float* __restrict__ pred = (s == 0) ? pred1 : (s == 1) ? pred2 : pred3;
    const float* __restrict__ anc  = (s == 0) ? anc1  : (s == 1) ? anc2  : anc3;
    const int W  = 56 >> s;
    const int HW = W * W;
    const int A  = HW * 3;

    __shared__ float          s_objx[MAXA];
    __shared__ unsigned char  s_matched[MAXA];
    __shared__ unsigned char  s_flags[MAXA];   // bit0 = pos, bit1 = neg
    __shared__ float4         s_boxes[T];
    __shared__ int            s_labels[T];
    __shared__ unsigned long long s_wbest[4][T];
    __shared__ unsigned       s_besta[T];
    __shared__ unsigned       s_redu[5];
    __shared__ float          s_redf[16];

    const int tid  = threadIdx.x;
    const int lane = tid & 63;
    const int wid  = tid >> 6;

    if (tid < T) {
        const float* bp_ = tboxes + (size_t)(b * T + tid) * 4;
        s_boxes[tid]  = make_float4(bp_[0], bp_[1], bp_[2], bp_[3]);
        s_labels[tid] = tlabels[b * T + tid];
    }
    __syncthreads();

    // ---------------- Pass 1: IoU, per-anchor argmax, per-box best ----------
    unsigned long long bp[T];
#pragma unroll
    for (int t = 0; t < T; t++) bp[t] = 0ull;

    const float* objbase = pred + (size_t)(b * 24 + 4) * HW;  // + k*8*HW + pix

    {
#pragma clang fp contract(off)
        for (int j = tid; j < A; j += 256) {
            int k   = (j >= 2 * HW) ? 2 : (j >= HW ? 1 : 0);
            int pix = j - k * HW;
            int a   = pix * 3 + k;
            float x = objbase[(size_t)k * 8 * HW + pix];
            float4 an = ((const float4*)anc)[a];
            float area_a = (an.z - an.x) * (an.w - an.y);
            float maxv = -1.f;
            int argt = 0;
#pragma unroll
            for (int t = 0; t < T; t++) {
                float4 g = s_boxes[t];
                float lx = fmaxf(an.x, g.x), ly = fmaxf(an.y, g.y);
                float rx = fminf(an.z, g.z), ry = fminf(an.w, g.w);
                float w = fmaxf(rx - lx, 0.f), h = fmaxf(ry - ly, 0.f);
                float inter  = w * h;
                float area_b = (g.z - g.x) * (g.w - g.y);
                float iou = inter / (((area_a + area_b) - inter) + 1e-9f);
                if (iou > maxv) { maxv = iou; argt = t; }  // first-max tiebreak
                // total order: iou desc, then anchor index asc (iou >= 0)
                unsigned long long pk =
                    ((unsigned long long)__float_as_uint(iou) << 32) |
                    (unsigned long long)(0xFFFFFFFFu - (unsigned)a);
                if (pk > bp[t]) bp[t] = pk;
            }
            s_objx[a]    = x;
            s_matched[a] = (unsigned char)argt;
            s_flags[a]   = (unsigned char)((maxv >= 0.5f ? 1 : 0) |
                                           (maxv <  0.3f ? 2 : 0));
        }
    }

    // wave-level reduce of per-box best, then cross-wave
#pragma unroll
    for (int t = 0; t < T; t++) {
        unsigned long long v = bp[t];
        for (int off = 32; off > 0; off >>= 1) {
            unsigned long long o = __shfl_down(v, off, 64);
            if (o > v) v = o;
        }
        if (lane == 0) s_wbest[wid][t] = v;
    }
    __syncthreads();
    if (tid < T) {
        unsigned long long v = s_wbest[0][tid];
        for (int w2 = 1; w2 < 4; w2++) {
            unsigned long long o = s_wbest[w2][tid];
            if (o > v) v = o;
        }
        s_besta[tid] = 0xFFFFFFFFu - (unsigned)(v & 0xFFFFFFFFull);
    }
    __syncthreads();
    // sequential overrides: numpy fancy-assignment last-wins semantics
    if (tid == 0) {
        for (int t = 0; t < T; t++) {
            unsigned a = s_besta[t];
            s_matched[a] = (unsigned char)t;
            s_flags[a]   = 1;  // pos=1, neg=0
        }
    }
    __syncthreads();

    // ---------------- Pass 2: counts ----------------------------------------
    unsigned cnt = 0;
    for (int a = tid; a < A; a += 256) {
        unsigned f = s_flags[a];
        cnt += (f & 1u) + ((f & 2u) ? 0x10000u : 0u);
    }
    for (int off = 32; off > 0; off >>= 1) cnt += __shfl_down(cnt, off, 64);
    if (lane == 0) s_redu[wid] = cnt;
    __syncthreads();
    if (tid == 0) s_redu[4] = s_redu[0] + s_redu[1] + s_redu[2] + s_redu[3];
    __syncthreads();
    unsigned both = s_redu[4];
    unsigned np   = both & 0xFFFFu;
    unsigned nn   = both >> 16;
    unsigned need = min(3u * np, nn);

    // ---------------- Pass 3: exact k-th largest neg logit (binary search) --
    unsigned kth = 0xFFFFFFFFu;  // sentinel: nothing selected when need==0
    if (need > 0) {
        unsigned lo = 0u, hi = 0xFFFFFFFFu;
        while (lo < hi) {
            unsigned d   = hi - lo;
            unsigned mid = lo + (d >> 1) + (d & 1u);  // ceil-mid, no overflow
            unsigned c = 0;
            for (int a = tid; a < A; a += 256) {
                if ((s_flags[a] & 2u) && mapf(s_objx[a]) >= mid) c++;
            }
            for (int off = 32; off > 0; off >>= 1) c += __shfl_down(c, off, 64);
            if (lane == 0) s_redu[wid] = c;
            __syncthreads();
            if (tid == 0) s_redu[4] = s_redu[0] + s_redu[1] + s_redu[2] + s_redu[3];
            __syncthreads();
            c = s_redu[4];
            if (c >= need) lo = mid; else hi = mid - 1;
        }
        kth = lo;
    }

    // ---------------- Pass 4: losses ----------------------------------------
    float obj_s = 0.f, cls_s = 0.f, loc_s = 0.f;
    unsigned cgt = 0;
    for (int a = tid; a < A; a += 256) {
        unsigned f = s_flags[a];
        if (f & 1u) {
            float x = s_objx[a];
            obj_s += bce_pos(x);
            int t   = s_matched[a];
            float4 g = s_boxes[t];
            int tgt = s_labels[t] - 1;
            int pix = a / 3;
            int k   = a - pix * 3;
            const float* base = pred + (size_t)(b * 24 + k * 8) * HW + pix;
            // classification CE (log_softmax over 3 classes)
            float c0 = base[5 * HW], c1 = base[6 * HW], c2 = base[7 * HW];
            float m   = fmaxf(c0, fmaxf(c1, c2));
            float lse = logf(expf(c0 - m) + expf(c1 - m) + expf(c2 - m));
            float ct  = (tgt == 0) ? c0 : (tgt == 1) ? c1 : c2;
            cls_s += (m + lse) - ct;
            // localization smooth-L1 vs encoded target
            float d0 = base[0], d1 = base[HW], d2 = base[2 * HW], d3 = base[3 * HW];
            float4 an = ((const float4*)anc)[a];
            float aw = an.z - an.x, ah = an.w - an.y;
            float acx = (an.x + an.z) * 0.5f, acy = (an.y + an.w) * 0.5f;
            float gw = g.z - g.x, gh = g.w - g.y;
            float gcx = (g.x + g.z) * 0.5f, gcy = (g.y + g.w) * 0.5f;
            float t0 = (gcx - acx) / aw, t1 = (gcy - acy) / ah;
            float t2 = logf(gw / aw),    t3 = logf(gh / ah);
            float dd;
            dd = fabsf(d0 - t0); loc_s += (dd < 1.f) ? 0.5f * dd * dd : dd - 0.5f;
            dd = fabsf(d1 - t1); loc_s += (dd < 1.f) ? 0.5f * dd * dd : dd - 0.5f;
            dd = fabsf(d2 - t2); loc_s += (dd < 1.f) ? 0.5f * dd * dd : dd - 0.5f;
            dd = fabsf(d3 - t3); loc_s += (dd < 1.f) ? 0.5f * dd * dd : dd - 0.5f;
        } else if (f & 2u) {
            float x = s_objx[a];
            if (mapf(x) > kth) { obj_s += bce_neg(x); cgt++; }
        }
    }
    for (int off = 32; off > 0; off >>= 1) {
        obj_s += __shfl_down(obj_s, off, 64);
        cls_s += __shfl_down(cls_s, off, 64);
        loc_s += __shfl_down(loc_s, off, 64);
        cgt   += __shfl_down(cgt,   off, 64);
    }
    if (lane == 0) {
        s_redf[wid * 4 + 0] = obj_s;
        s_redf[wid * 4 + 1] = cls_s;
        s_redf[wid * 4 + 2] = loc_s;
        s_redf[wid * 4 + 3] = __uint_as_float(cgt);
    }
    __syncthreads();
    if (tid == 0) {
        float ob = 0.f, cl = 0.f, lc = 0.f;
        unsigned cg = 0;
        for (int w2 = 0; w2 < 4; w2++) {
            ob += s_redf[w2 * 4 + 0];
            cl += s_redf[w2 * 4 + 1];
            lc += s_redf[w2 * 4 + 2];
            cg += __float_as_uint(s_redf[w2 * 4 + 3]);
        }
        if (need > 0) ob += (float)(need - cg) * bce_neg(unmapf(kth));
        float obj_img = ob / (float)max(np + need, 1u);
        float cls_img = cl / (float)max(np, 1u);
        float loc_img = lc / (float)max(4u * np, 1u);
        atomicAdd(acc + 0, obj_img);
        atomicAdd(acc + 1, cls_img);
        atomicAdd(acc + 2, loc_img);
    }
}

__global__ void init_acc_kernel(float* acc) {
    if (threadIdx.x < 3) acc[threadIdx.x] = 0.f;
}

__global__ void finalize_kernel(const float* __restrict__ acc,
                                float* __restrict__ out) {
    if (threadIdx.x == 0) {
        float obj = acc[0] / 64.f;
        float cls = acc[1] / 64.f;
        float loc = acc[2] / 64.f;
        out[0] = obj;
        out[1] = cls;
        out[2] = loc;
        out[3] = obj + cls + 2.f * loc;
    }
}

extern "C" void kernel_launch(void* const* d_in, const int* in_sizes, int n_in,
                              void* d_out, int out_size, void* d_ws, size_t ws_size,
                              hipStream_t stream) {
    const float* pred1   = (const float*)d_in[0];
    const float* pred2   = (const float*)d_in[1];
    const float* pred3   = (const float*)d_in[2];
    const float* anchor1 = (const float*)d_in[3];
    const float* anchor2 = (const float*)d_in[4];
    const float* anchor3 = (const float*)d_in[5];
    const float* tboxes  = (const float*)d_in[6];
    const int*   tlabels = (const int*)d_in[7];
    float* acc = (float*)d_ws;
    float* out = (float*)d_out;

    init_acc_kernel<<<1, 64, 0, stream>>>(acc);
    det_loss_kernel<<<64 * 3, 256, 0, stream>>>(
        pred1, pred2, pred3, anchor1, anchor2, anchor3, tboxes, tlabels, acc);
    finalize_kernel<<<1, 64, 0, stream>>>(acc, out);
}

// Round 2
// 148.221 us; speedup vs baseline: 2.0239x; 2.0239x over previous
//
#include <hip/hip_runtime.h>
#include <math.h>

#define T 20
#define MAXA 9408
#define NT 1024

__device__ __forceinline__ unsigned mapf(float x) {
    unsigned u = __float_as_uint(x);
    return (u & 0x80000000u) ? ~u : (u | 0x80000000u);
}
__device__ __forceinline__ float unmapf(unsigned m) {
    return __uint_as_float((m & 0x80000000u) ? (m ^ 0x80000000u) : ~m);
}
__device__ __forceinline__ float bce_pos(float x) {
    return fmaxf(x, 0.f) - x + log1pf(expf(-fabsf(x)));
}
__device__ __forceinline__ float bce_neg(float x) {
    return fmaxf(x, 0.f) + log1pf(expf(-fabsf(x)));
}

__global__ __launch_bounds__(NT, 4) void det_loss_kernel(
    const float* __restrict__ pred1, const float* __restrict__ pred2,
    const float* __restrict__ pred3,
    const float* __restrict__ tboxes, const int* __restrict__ tlabels,
    float* __restrict__ acc)
{
#pragma clang fp contract(off)
    const int bid = blockIdx.x;
    const int b = bid / 3;
    const int s = bid - 3 * b;
    const float* __restrict__ pred = (s == 0) ? pred1 : (s == 1) ? pred2 : pred3;
    const int W = 56 >> s, HW = W * W, A = 3 * HW;
    const float stf = (float)(8 << s);
    const int sh = 3 - s;  // pix>>sh then /7 gives row

    __shared__ unsigned       s_key[MAXA];   // mapped obj key if neg else 0
    __shared__ unsigned short s_mf[MAXA];    // matched_t | pos<<8 | neg<<9
    __shared__ float4         s_box[T];
    __shared__ float          s_ab[T];
    __shared__ int            s_lab[T];
    __shared__ int            s_besta[T];
    __shared__ unsigned       s_cnt[33];     // [0..31] binsearch, [32] np|nn
    __shared__ float          s_redf[16 * 4];

    const int tid = threadIdx.x, lane = tid & 63, wid = tid >> 6;

    if (tid < T) {
        float4 g = ((const float4*)tboxes)[b * T + tid];
        s_box[tid] = g;
        s_ab[tid]  = (g.z - g.x) * (g.w - g.y);
        s_lab[tid] = tlabels[b * T + tid];
    }
    if (tid >= 64 && tid < 64 + 33) s_cnt[tid - 64] = 0;
    __syncthreads();

    const float* objbase = pred + (size_t)(b * 24 + 4) * HW;

    // ---------- Pass 1a: per-anchor argmax/flags (4 anchors/thread/iter) ----
    for (int i = 0; i < 3; i++) {
        int j0 = i * 4096 + tid;
        if (j0 >= A) break;
        float ax[4], ay[4], az[4], aw4[4], area[4], xo[4];
        int   kk[4], ppix[4];
#pragma unroll
        for (int q = 0; q < 4; q++) {
            int j  = j0 + q * 1024;
            int jj = (j < A) ? j : 0;
            int k   = (jj >= HW) + (jj >= 2 * HW);
            int pix = jj - k * HW;
            int qq  = pix >> sh;
            int py  = (qq * 9363) >> 16;      // exact /7 for qq<=448
            int px  = pix - py * W;
            float w  = (2.0f + 0.5f * (float)k) * stf;   // exact f32
            float cx = ((float)px + 0.5f) * stf;
            float cy = ((float)py + 0.5f) * stf;
            ax[q] = cx - 0.5f * w; ay[q] = cy - 0.5f * w;
            az[q] = cx + 0.5f * w; aw4[q] = cy + 0.5f * w;
            area[q] = w * w;
            kk[q] = k; ppix[q] = pix;
            xo[q] = objbase[(size_t)k * 8 * HW + pix];
        }
        float bn[4] = {-1.f, -1.f, -1.f, -1.f};
        float bu[4] = {1.f, 1.f, 1.f, 1.f};
        int   at_[4] = {0, 0, 0, 0};
        for (int t = 0; t < T; t++) {
            float4 g = s_box[t];
            float  ab = s_ab[t];
#pragma unroll
            for (int q = 0; q < 4; q++) {
                float lx = fmaxf(ax[q], g.x), ly = fmaxf(ay[q], g.y);
                float rx = fminf(az[q], g.z), ry = fminf(aw4[q], g.w);
                float ww = fmaxf(rx - lx, 0.f), hh = fmaxf(ry - ly, 0.f);
                float inter = ww * hh;
                float u = ((area[q] + ab) - inter) + 1e-9f;
                if (inter * bu[q] > bn[q] * u) { bn[q] = inter; bu[q] = u; at_[q] = t; }
            }
        }
#pragma unroll
        for (int q = 0; q < 4; q++) {
            int j = j0 + q * 1024;
            if (j < A) {
                bool pos = (bn[q] + bn[q] >= bu[q]);        // max_iou >= 0.5
                bool neg = (bn[q] < 0.3f * bu[q]);          // max_iou <  0.3
                s_key[j] = neg ? mapf(xo[q]) : 0u;
                s_mf[j]  = (unsigned short)(at_[q] | (pos ? 0x100 : 0) | (neg ? 0x200 : 0));
            }
        }
    }

    // ---------- Pass 1b: per-box best anchor (windowed, one wave per box) ---
    for (int t = wid; t < T; t += 16) {
        float4 g = s_box[t];
        float  ab = s_ab[t];
        int px0 = max(0, (int)floorf(g.x / stf) - 2);
        int px1 = min(W - 1, (int)floorf(g.z / stf) + 2);
        int py0 = max(0, (int)floorf(g.y / stf) - 2);
        int py1 = min(W - 1, (int)floorf(g.w / stf) + 2);
        int nx = px1 - px0 + 1, rowlen = nx * 3;
        float bi = -1.f, bu2 = 1.f;
        int ba = 0;
        for (int py = py0; py <= py1; py++) {
            float cy = ((float)py + 0.5f) * stf;
            for (int c = lane; c < rowlen; c += 64) {
                int ix = (c * 21846) >> 16;  // /3
                int k  = c - 3 * ix;
                int px = px0 + ix;
                float w  = (2.0f + 0.5f * (float)k) * stf;
                float cx = ((float)px + 0.5f) * stf;
                float lx = fmaxf(cx - 0.5f * w, g.x), ly = fmaxf(cy - 0.5f * w, g.y);
                float rx = fminf(cx + 0.5f * w, g.z), ry = fminf(cy + 0.5f * w, g.w);
                float ww = fmaxf(rx - lx, 0.f), hh = fmaxf(ry - ly, 0.f);
                float inter = ww * hh;
                float u = ((w * w + ab) - inter) + 1e-9f;
                if (inter * bu2 > bi * u) {
                    bi = inter; bu2 = u; ba = (py * W + px) * 3 + k;
                }
            }
        }
        for (int off = 32; off; off >>= 1) {
            float oi = __shfl_down(bi, off, 64);
            float ou = __shfl_down(bu2, off, 64);
            int   oa = __shfl_down(ba, off, 64);
            float l = oi * bu2, r = bi * ou;
            if (l > r || (l == r && oa < ba)) { bi = oi; bu2 = ou; ba = oa; }
        }
        if (lane == 0) s_besta[t] = ba;
    }
    __syncthreads();

    // ---------- forced-positive overrides (last-wins, ascending t) ----------
    if (tid == 0) {
        for (int t = 0; t < T; t++) {
            int a = s_besta[t];
            int pix = (a * 21846) >> 16;  // /3
            int k = a - 3 * pix;
            int j = k * HW + pix;
            s_mf[j]  = (unsigned short)(t | 0x100);
            s_key[j] = 0u;
        }
    }
    __syncthreads();

    // ---------- refresh keys to registers + count np/nn ---------------------
    unsigned keyreg[12];
#pragma unroll
    for (int m = 0; m < 12; m++) keyreg[m] = 0u;
    unsigned npnn = 0;
#pragma unroll
    for (int i = 0; i < 3; i++) {
#pragma unroll
        for (int q = 0; q < 4; q++) {
            int j = i * 4096 + q * 1024 + tid;
            if (j < A) {
                unsigned mf = s_mf[j];
                keyreg[i * 4 + q] = s_key[j];
                npnn += ((mf >> 8) & 1u) + (((mf >> 9) & 1u) << 16);
            }
        }
    }
    for (int off = 32; off; off >>= 1) npnn += (unsigned)__shfl_down((int)npnn, off, 64);
    if (lane == 0) atomicAdd(&s_cnt[32], npnn);
    __syncthreads();
    unsigned np = s_cnt[32] & 0xFFFFu, nn = s_cnt[32] >> 16;
    unsigned need = min(3u * np, nn);

    // ---------- exact k-th largest neg key (register binary search) ---------
    unsigned kth = 0xFFFFFFFFu;
    if (need > 0) {
        unsigned lo = 0u, hi = 0xFFFFFFFFu;
        int it = 0;
        while (lo < hi) {
            unsigned d = hi - lo;
            unsigned mid = lo + (d >> 1) + (d & 1u);
            unsigned c = 0;
#pragma unroll
            for (int m = 0; m < 12; m++) c += (keyreg[m] >= mid) ? 1u : 0u;
            for (int off = 32; off; off >>= 1) c += (unsigned)__shfl_down((int)c, off, 64);
            if (lane == 0) atomicAdd(&s_cnt[it], c);
            __syncthreads();
            c = s_cnt[it]; it++;
            if (c >= need) lo = mid; else hi = mid - 1;
        }
        kth = lo;
    }

    // ---------- Pass 4: losses ----------------------------------------------
    float obj_s = 0.f, cls_s = 0.f, loc_s = 0.f;
    unsigned cgt = 0;
    for (int j = tid; j < A; j += NT) {
        unsigned mf = s_mf[j];
        if (mf & 0x100u) {
            int k = (j >= HW) + (j >= 2 * HW);
            int pix = j - k * HW;
            const float* base = pred + (size_t)(b * 24 + k * 8) * HW + pix;
            float x = base[(size_t)4 * HW];
            obj_s += bce_pos(x);
            int t = mf & 0xFFu;
            float4 g = s_box[t];
            int tgt = s_lab[t] - 1;
            float c0 = base[(size_t)5 * HW], c1 = base[(size_t)6 * HW], c2 = base[(size_t)7 * HW];
            float m  = fmaxf(c0, fmaxf(c1, c2));
            float lse = logf(expf(c0 - m) + expf(c1 - m) + expf(c2 - m));
            float ct = (tgt == 0) ? c0 : (tgt == 1) ? c1 : c2;
            cls_s += (m + lse) - ct;
            int qq = pix >> sh;
            int py = (qq * 9363) >> 16;
            int px = pix - py * W;
            float w  = (2.0f + 0.5f * (float)k) * stf;
            float cx = ((float)px + 0.5f) * stf;
            float cy = ((float)py + 0.5f) * stf;
            float gcx = (g.x + g.z) * 0.5f, gcy = (g.y + g.w) * 0.5f;
            float gw = g.z - g.x, gh = g.w - g.y;
            float t0 = (gcx - cx) / w, t1 = (gcy - cy) / w;
            float t2 = logf(gw / w),   t3 = logf(gh / w);
            float d0 = base[0], d1 = base[(size_t)HW], d2 = base[(size_t)2 * HW], d3 = base[(size_t)3 * HW];
            float dd;
            dd = fabsf(d0 - t0); loc_s += (dd < 1.f) ? 0.5f * dd * dd : dd - 0.5f;
            dd = fabsf(d1 - t1); loc_s += (dd < 1.f) ? 0.5f * dd * dd : dd - 0.5f;
            dd = fabsf(d2 - t2); loc_s += (dd < 1.f) ? 0.5f * dd * dd : dd - 0.5f;
            dd = fabsf(d3 - t3); loc_s += (dd < 1.f) ? 0.5f * dd * dd : dd - 0.5f;
        } else {
            unsigned key = s_key[j];
            if (key > kth) { obj_s += bce_neg(unmapf(key)); cgt++; }
        }
    }
    for (int off = 32; off; off >>= 1) {
        obj_s += __shfl_down(obj_s, off, 64);
        cls_s += __shfl_down(cls_s, off, 64);
        loc_s += __shfl_down(loc_s, off, 64);
        cgt   += (unsigned)__shfl_down((int)cgt, off, 64);
    }
    if (lane == 0) {
        s_redf[wid * 4 + 0] = obj_s;
        s_redf[wid * 4 + 1] = cls_s;
        s_redf[wid * 4 + 2] = loc_s;
        s_redf[wid * 4 + 3] = __uint_as_float(cgt);
    }
    __syncthreads();
    if (tid == 0) {
        float ob = 0.f, cl = 0.f, lc = 0.f;
        unsigned cg = 0;
        for (int w2 = 0; w2 < 16; w2++) {
            ob += s_redf[w2 * 4 + 0];
            cl += s_redf[w2 * 4 + 1];
            lc += s_redf[w2 * 4 + 2];
            cg += __float_as_uint(s_redf[w2 * 4 + 3]);
        }
        if (need > 0) ob += (float)(need - cg) * bce_neg(unmapf(kth));
        atomicAdd(acc + 0, ob / (float)max(np + need, 1u));
        atomicAdd(acc + 1, cl / (float)max(np, 1u));
        atomicAdd(acc + 2, lc / (float)max(4u * np, 1u));
    }
}

__global__ void init_acc_kernel(float* acc) {
    if (threadIdx.x < 3) acc[threadIdx.x] = 0.f;
}

__global__ void finalize_kernel(const float* __restrict__ acc,
                                float* __restrict__ out) {
    if (threadIdx.x == 0) {
        float obj = acc[0] / 64.f;
        float cls = acc[1] / 64.f;
        float loc = acc[2] / 64.f;
        out[0] = obj;
        out[1] = cls;
        out[2] = loc;
        out[3] = obj + cls + 2.f * loc;
    }
}

extern "C" void kernel_launch(void* const* d_in, const int* in_sizes, int n_in,
                              void* d_out, int out_size, void* d_ws, size_t ws_size,
                              hipStream_t stream) {
    const float* pred1   = (const float*)d_in[0];
    const float* pred2   = (const float*)d_in[1];
    const float* pred3   = (const float*)d_in[2];
    const float* tboxes  = (const float*)d_in[6];
    const int*   tlabels = (const int*)d_in[7];
    float* acc = (float*)d_ws;
    float* out = (float*)d_out;

    init_acc_kernel<<<1, 64, 0, stream>>>(acc);
    det_loss_kernel<<<64 * 3, NT, 0, stream>>>(
        pred1, pred2, pred3, tboxes, tlabels, acc);
    finalize_kernel<<<1, 64, 0, stream>>>(acc, out);
}

// Round 3
// 139.511 us; speedup vs baseline: 2.1503x; 1.0624x over previous
//
#include <hip/hip_runtime.h>
#include <math.h>

#define T 20
#define APB 12348            // anchors per image (9408+2352+588)
#define NPNN_OFF 64          // u32 index into ws
#define KEY_OFF  256         // u32 index into ws
#define MF_BYTE_OFF (4 * (KEY_OFF + 64 * APB))

__device__ __forceinline__ unsigned mapf(float x) {
    unsigned u = __float_as_uint(x);
    return (u & 0x80000000u) ? ~u : (u | 0x80000000u);
}
__device__ __forceinline__ float unmapf(unsigned m) {
    return __uint_as_float((m & 0x80000000u) ? (m ^ 0x80000000u) : ~m);
}
__device__ __forceinline__ float bce_pos(float x) {
    return fmaxf(x, 0.f) - x + log1pf(expf(-fabsf(x)));
}
__device__ __forceinline__ float bce_neg(float x) {
    return fmaxf(x, 0.f) + log1pf(expf(-fabsf(x)));
}

// ---------------------------------------------------------------------------
// K1: per-anchor matching. 704 blocks x 256. Chunk = 1176 anchors, 5/thread.
// ---------------------------------------------------------------------------
__global__ __launch_bounds__(256) void match_kernel(
    const float* __restrict__ pred1, const float* __restrict__ pred2,
    const float* __restrict__ pred3, const float* __restrict__ tboxes,
    unsigned* __restrict__ wsu, unsigned short* __restrict__ mf)
{
#pragma clang fp contract(off)
    const int blk = blockIdx.x;
    const int b = blk / 11, c = blk - 11 * b;
    int s, j0;
    if (c < 8)       { s = 0; j0 = c * 1176; }
    else if (c < 10) { s = 1; j0 = (c - 8) * 1176; }
    else             { s = 2; j0 = 0; }
    const float* __restrict__ pred = (s == 0) ? pred1 : (s == 1) ? pred2 : pred3;
    const int W = 56 >> s, HW = W * W, A = 3 * HW;
    const float stf = (float)(8 << s);
    const int sh = 3 - s;
    const int lim = min(1176, A - j0);

    __shared__ float4 s_box[T];
    __shared__ float  s_ab[T];
    const int tid = threadIdx.x, lane = tid & 63;

    if (tid < T) {
        float4 g = ((const float4*)tboxes)[b * T + tid];
        s_box[tid] = g;
        s_ab[tid]  = (g.z - g.x) * (g.w - g.y);
    }
    __syncthreads();

    float ax[5], ay[5], az[5], aw[5], ar[5], bn[5], bu[5];
    int at_[5], jj[5];
#pragma unroll
    for (int q = 0; q < 5; q++) {
        int o = tid + q * 256;
        int j = j0 + ((o < lim) ? o : 0);
        jj[q] = j;
        int k   = (j >= HW) + (j >= 2 * HW);
        int pix = j - k * HW;
        int qq  = pix >> sh;
        int py  = (qq * 9363) >> 16;
        int px  = pix - py * W;
        float w  = (2.0f + 0.5f * (float)k) * stf;
        float cx = ((float)px + 0.5f) * stf;
        float cy = ((float)py + 0.5f) * stf;
        ax[q] = cx - 0.5f * w; ay[q] = cy - 0.5f * w;
        az[q] = cx + 0.5f * w; aw[q] = cy + 0.5f * w;
        ar[q] = w * w;
        bn[q] = -1.f; bu[q] = 1.f; at_[q] = 0;
    }
    for (int t = 0; t < T; t++) {
        float4 g = s_box[t];
        float  ab = s_ab[t];
#pragma unroll
        for (int q = 0; q < 5; q++) {
            float lx = fmaxf(ax[q], g.x), ly = fmaxf(ay[q], g.y);
            float rx = fminf(az[q], g.z), ry = fminf(aw[q], g.w);
            float ww = fmaxf(rx - lx, 0.f), hh = fmaxf(ry - ly, 0.f);
            float inter = ww * hh;
            float u = ((ar[q] + ab) - inter) + 1e-9f;
            if (inter * bu[q] > bn[q] * u) { bn[q] = inter; bu[q] = u; at_[q] = t; }
        }
    }

    const float* objbase = pred + (size_t)(b * 24 + 4) * HW;
    const unsigned base = (unsigned)(b * APB + ((s == 0) ? 0 : (s == 1) ? 9408 : 11760));
    unsigned npnn = 0;
#pragma unroll
    for (int q = 0; q < 5; q++) {
        int o = tid + q * 256;
        if (o < lim) {
            int j = jj[q];
            int k   = (j >= HW) + (j >= 2 * HW);
            int pix = j - k * HW;
            bool pos = (bn[q] + bn[q] >= bu[q]);   // max_iou >= 0.5
            bool neg = (bn[q] < 0.3f * bu[q]);     // max_iou <  0.3
            float x = objbase[(size_t)k * 8 * HW + pix];
            wsu[KEY_OFF + base + j] = neg ? mapf(x) : 0u;
            mf[base + j] = (unsigned short)(at_[q] | (pos ? 0x100 : 0) | (neg ? 0x200 : 0));
            npnn += (pos ? 1u : 0u) + (neg ? 0x10000u : 0u);
        }
    }
    for (int off = 32; off; off >>= 1) npnn += (unsigned)__shfl_down((int)npnn, off, 64);
    if (lane == 0) atomicAdd(&wsu[NPNN_OFF + b * 3 + s], npnn);
}

// ---------------------------------------------------------------------------
// K2: per-(b,s) forced positives + hard-neg mining + losses. 192 x 1024.
// ---------------------------------------------------------------------------
__global__ __launch_bounds__(1024) void select_loss_kernel(
    const float* __restrict__ pred1, const float* __restrict__ pred2,
    const float* __restrict__ pred3, const float* __restrict__ tboxes,
    const int* __restrict__ tlabels,
    unsigned* __restrict__ wsu, unsigned short* __restrict__ mf,
    float* __restrict__ acc)
{
#pragma clang fp contract(off)
    const int bid = blockIdx.x;
    const int b = bid / 3, s = bid - 3 * b;
    const float* __restrict__ pred = (s == 0) ? pred1 : (s == 1) ? pred2 : pred3;
    const int W = 56 >> s, HW = W * W, A = 3 * HW;
    const float stf = (float)(8 << s);
    const int sh = 3 - s;
    const unsigned base = (unsigned)(b * APB + ((s == 0) ? 0 : (s == 1) ? 9408 : 11760));

    __shared__ float4   s_box[T];
    __shared__ int      s_lab[T];
    __shared__ int      s_besta[T];
    __shared__ unsigned s_cnt[33];   // [0..31] binsearch, [32] npnn adjust
    __shared__ float    s_redf[16 * 4];

    const int tid = threadIdx.x, lane = tid & 63, wid = tid >> 6;

    if (tid < T) {
        s_box[tid] = ((const float4*)tboxes)[b * T + tid];
        s_lab[tid] = tlabels[b * T + tid];
    }
    if (tid >= 64 && tid < 64 + 33) s_cnt[tid - 64] = 0;
    __syncthreads();

    // ---- windowed per-box best anchor (one wave per box) -------------------
    for (int t = wid; t < T; t += 16) {
        float4 g = s_box[t];
        float  ab = (g.z - g.x) * (g.w - g.y);
        int px0 = max(0, (int)floorf(g.x / stf) - 2);
        int px1 = min(W - 1, (int)floorf(g.z / stf) + 2);
        int py0 = max(0, (int)floorf(g.y / stf) - 2);
        int py1 = min(W - 1, (int)floorf(g.w / stf) + 2);
        int rowlen = (px1 - px0 + 1) * 3;
        float bi = -1.f, bu2 = 1.f;
        int ba = 0;
        for (int py = py0; py <= py1; py++) {
            float cy = ((float)py + 0.5f) * stf;
            for (int cc = lane; cc < rowlen; cc += 64) {
                int ix = (cc * 21846) >> 16;
                int k  = cc - 3 * ix;
                int px = px0 + ix;
                float w  = (2.0f + 0.5f * (float)k) * stf;
                float cx = ((float)px + 0.5f) * stf;
                float lx = fmaxf(cx - 0.5f * w, g.x), ly = fmaxf(cy - 0.5f * w, g.y);
                float rx = fminf(cx + 0.5f * w, g.z), ry = fminf(cy + 0.5f * w, g.w);
                float ww = fmaxf(rx - lx, 0.f), hh = fmaxf(ry - ly, 0.f);
                float inter = ww * hh;
                float u = ((w * w + ab) - inter) + 1e-9f;
                if (inter * bu2 > bi * u) {
                    bi = inter; bu2 = u; ba = (py * W + px) * 3 + k;
                }
            }
        }
        for (int off = 32; off; off >>= 1) {
            float oi = __shfl_down(bi, off, 64);
            float ou = __shfl_down(bu2, off, 64);
            int   oa = __shfl_down(ba, off, 64);
            float l = oi * bu2, r = bi * ou;
            if (l > r || (l == r && oa < ba)) { bi = oi; bu2 = ou; ba = oa; }
        }
        if (lane == 0) s_besta[t] = ba;
    }
    __syncthreads();

    // ---- apply overrides in parallel (first/winner duplicate resolution) ---
    int  j20 = 0; bool winner = false;
    if (tid < T) {
        int a = s_besta[tid];
        winner = true; bool first = true;
        for (int t2 = tid + 1; t2 < T; t2++) if (s_besta[t2] == a) winner = false;
        for (int t2 = 0; t2 < tid; t2++)     if (s_besta[t2] == a) first  = false;
        int pix = (a * 21846) >> 16;
        int k = a - 3 * pix;
        j20 = k * HW + pix;
        if (first) {
            unsigned old = mf[base + j20];
            unsigned d = ((old & 0x100u) ? 0u : 1u) +
                         ((old & 0x200u) ? 0xFFFF0000u : 0u);  // nn -= 1
            atomicAdd(&s_cnt[32], d);
        }
    }
    __syncthreads();
    if (tid < T && winner) {
        mf[base + j20] = (unsigned short)(tid | 0x100);
        wsu[KEY_OFF + base + j20] = 0u;
    }
    __threadfence_block();
    __syncthreads();

    unsigned packed = wsu[NPNN_OFF + bid] + s_cnt[32];
    unsigned np = packed & 0xFFFFu, nn = packed >> 16;
    unsigned need = min(3u * np, nn);

    // ---- load keys to registers -------------------------------------------
    unsigned keyreg[10];
#pragma unroll
    for (int m = 0; m < 10; m++) {
        int j = tid + m * 1024;
        keyreg[m] = (j < A) ? wsu[KEY_OFF + base + j] : 0u;
    }

    // ---- exact k-th largest neg key (binary search) ------------------------
    unsigned kth = 0xFFFFFFFFu;
    if (need > 0) {
        unsigned lo = 0u, hi = 0xFFFFFFFFu;
        int it = 0;
        while (lo < hi) {
            unsigned d = hi - lo;
            unsigned mid = lo + (d >> 1) + (d & 1u);
            unsigned cnt = 0;
#pragma unroll
            for (int m = 0; m < 10; m++) cnt += (keyreg[m] >= mid) ? 1u : 0u;
            for (int off = 32; off; off >>= 1) cnt += (unsigned)__shfl_down((int)cnt, off, 64);
            if (lane == 0) atomicAdd(&s_cnt[it], cnt);
            __syncthreads();
            cnt = s_cnt[it]; it++;
            if (cnt >= need) lo = mid; else hi = mid - 1;
        }
        kth = lo;
    }

    // ---- losses ------------------------------------------------------------
    float obj_s = 0.f, cls_s = 0.f, loc_s = 0.f;
    unsigned cgt = 0;
#pragma unroll 1
    for (int m = 0; m < 10; m++) {
        int j = tid + m * 1024;
        if (j >= A) break;
        unsigned mfv = mf[base + j];
        if (mfv & 0x100u) {
            int k   = (j >= HW) + (j >= 2 * HW);
            int pix = j - k * HW;
            const float* bp = pred + (size_t)(b * 24 + k * 8) * HW + pix;
            float x = bp[(size_t)4 * HW];
            obj_s += bce_pos(x);
            int t = mfv & 0xFFu;
            float4 g = s_box[t];
            int tgt = s_lab[t] - 1;
            float c0 = bp[(size_t)5 * HW], c1 = bp[(size_t)6 * HW], c2 = bp[(size_t)7 * HW];
            float mm  = fmaxf(c0, fmaxf(c1, c2));
            float lse = logf(expf(c0 - mm) + expf(c1 - mm) + expf(c2 - mm));
            float ct = (tgt == 0) ? c0 : (tgt == 1) ? c1 : c2;
            cls_s += (mm + lse) - ct;
            int qq = pix >> sh;
            int py = (qq * 9363) >> 16;
            int px = pix - py * W;
            float w  = (2.0f + 0.5f * (float)k) * stf;
            float cx = ((float)px + 0.5f) * stf;
            float cy = ((float)py + 0.5f) * stf;
            float gcx = (g.x + g.z) * 0.5f, gcy = (g.y + g.w) * 0.5f;
            float gw = g.z - g.x, gh = g.w - g.y;
            float t0 = (gcx - cx) / w, t1 = (gcy - cy) / w;
            float t2 = logf(gw / w),   t3 = logf(gh / w);
            float d0 = bp[0], d1 = bp[(size_t)HW], d2 = bp[(size_t)2 * HW], d3 = bp[(size_t)3 * HW];
            float dd;
            dd = fabsf(d0 - t0); loc_s += (dd < 1.f) ? 0.5f * dd * dd : dd - 0.5f;
            dd = fabsf(d1 - t1); loc_s += (dd < 1.f) ? 0.5f * dd * dd : dd - 0.5f;
            dd = fabsf(d2 - t2); loc_s += (dd < 1.f) ? 0.5f * dd * dd : dd - 0.5f;
            dd = fabsf(d3 - t3); loc_s += (dd < 1.f) ? 0.5f * dd * dd : dd - 0.5f;
        } else {
            unsigned key = keyreg[m];
            if (key > kth) { obj_s += bce_neg(unmapf(key)); cgt++; }
        }
    }
    for (int off = 32; off; off >>= 1) {
        obj_s += __shfl_down(obj_s, off, 64);
        cls_s += __shfl_down(cls_s, off, 64);
        loc_s += __shfl_down(loc_s, off, 64);
        cgt   += (unsigned)__shfl_down((int)cgt, off, 64);
    }
    if (lane == 0) {
        s_redf[wid * 4 + 0] = obj_s;
        s_redf[wid * 4 + 1] = cls_s;
        s_redf[wid * 4 + 2] = loc_s;
        s_redf[wid * 4 + 3] = __uint_as_float(cgt);
    }
    __syncthreads();
    if (tid == 0) {
        float ob = 0.f, cl = 0.f, lc = 0.f;
        unsigned cg = 0;
        for (int w2 = 0; w2 < 16; w2++) {
            ob += s_redf[w2 * 4 + 0];
            cl += s_redf[w2 * 4 + 1];
            lc += s_redf[w2 * 4 + 2];
            cg += __float_as_uint(s_redf[w2 * 4 + 3]);
        }
        if (need > 0) ob += (float)(need - cg) * bce_neg(unmapf(kth));
        atomicAdd(acc + 0, ob / (float)max(np + need, 1u));
        atomicAdd(acc + 1, cl / (float)max(np, 1u));
        atomicAdd(acc + 2, lc / (float)max(4u * np, 1u));
    }
}

__global__ void init_kernel(unsigned* __restrict__ wsu) {
    int tid = threadIdx.x;
    if (tid < 3) ((float*)wsu)[tid] = 0.f;
    if (tid >= NPNN_OFF && tid < NPNN_OFF + 192) wsu[tid] = 0u;
}

__global__ void finalize_kernel(const float* __restrict__ acc,
                                float* __restrict__ out) {
    if (threadIdx.x == 0) {
        float obj = acc[0] / 64.f;
        float cls = acc[1] / 64.f;
        float loc = acc[2] / 64.f;
        out[0] = obj;
        out[1] = cls;
        out[2] = loc;
        out[3] = obj + cls + 2.f * loc;
    }
}

extern "C" void kernel_launch(void* const* d_in, const int* in_sizes, int n_in,
                              void* d_out, int out_size, void* d_ws, size_t ws_size,
                              hipStream_t stream) {
    const float* pred1   = (const float*)d_in[0];
    const float* pred2   = (const float*)d_in[1];
    const float* pred3   = (const float*)d_in[2];
    const float* tboxes  = (const float*)d_in[6];
    const int*   tlabels = (const int*)d_in[7];
    unsigned* wsu = (unsigned*)d_ws;
    unsigned short* mf = (unsigned short*)((char*)d_ws + MF_BYTE_OFF);
    float* acc = (float*)d_ws;
    float* out = (float*)d_out;

    init_kernel<<<1, 256, 0, stream>>>(wsu);
    match_kernel<<<64 * 11, 256, 0, stream>>>(pred1, pred2, pred3, tboxes, wsu, mf);
    select_loss_kernel<<<64 * 3, 1024, 0, stream>>>(
        pred1, pred2, pred3, tboxes, tlabels, wsu, mf, acc);
    finalize_kernel<<<1, 64, 0, stream>>>(acc, out);
}

// Round 4
// 124.346 us; speedup vs baseline: 2.4125x; 1.1220x over previous
//
#include <hip/hip_runtime.h>
#include <math.h>

#define T 20
#define APB 12348            // anchors per image (9408+2352+588)
#define LOSS_OFF 16          // float index: 192*3 per-(b,s) loss triples
#define NPNN_OFF 640         // u32 index: 704 per-match-block npnn slots
#define KEY_OFF  2048        // u32 index: 64*APB keys
#define MF_BYTE_OFF (4 * (KEY_OFF + 64 * APB))

__device__ __forceinline__ unsigned mapf(float x) {
    unsigned u = __float_as_uint(x);
    return (u & 0x80000000u) ? ~u : (u | 0x80000000u);
}
__device__ __forceinline__ float unmapf(unsigned m) {
    return __uint_as_float((m & 0x80000000u) ? (m ^ 0x80000000u) : ~m);
}
__device__ __forceinline__ float bce_pos(float x) {
    return fmaxf(x, 0.f) - x + log1pf(expf(-fabsf(x)));
}
__device__ __forceinline__ float bce_neg(float x) {
    return fmaxf(x, 0.f) + log1pf(expf(-fabsf(x)));
}

// ---------------------------------------------------------------------------
// K1: per-anchor matching. 704 blocks x 256. Chunk = 1176 contiguous anchors,
// 5 CONTIGUOUS anchors/thread -> tight spatial band -> per-box skip test.
// ---------------------------------------------------------------------------
__global__ __launch_bounds__(256) void match_kernel(
    const float* __restrict__ pred1, const float* __restrict__ pred2,
    const float* __restrict__ pred3, const float* __restrict__ tboxes,
    unsigned* __restrict__ wsu, unsigned short* __restrict__ mf)
{
#pragma clang fp contract(off)
    const int blk = blockIdx.x;
    const int b = blk / 11, c = blk - 11 * b;
    int s, j0;
    if (c < 8)       { s = 0; j0 = c * 1176; }
    else if (c < 10) { s = 1; j0 = (c - 8) * 1176; }
    else             { s = 2; j0 = 0; }
    const float* __restrict__ pred = (s == 0) ? pred1 : (s == 1) ? pred2 : pred3;
    const int W = 56 >> s, HW = W * W, A = 3 * HW;
    const float stf = (float)(8 << s);
    const int sh = 3 - s;
    const int lim = min(1176, A - j0);

    __shared__ float4   s_box[T];
    __shared__ float    s_ab[T];
    __shared__ unsigned s_np[4];
    const int tid = threadIdx.x, lane = tid & 63, wid = tid >> 6;

    if (tid < T) {
        float4 g = ((const float4*)tboxes)[b * T + tid];
        s_box[tid] = g;
        s_ab[tid]  = (g.z - g.x) * (g.w - g.y);
    }
    __syncthreads();

    float ax[5], ay[5], az[5], aw[5], ar[5], bn[5], bu[5];
    int at_[5], kk[5], pp[5];
    bool vv[5];
    float xlo = 1e30f, xhi = -1e30f, ylo = 1e30f, yhi = -1e30f;
    const int obase = 5 * tid;
#pragma unroll
    for (int r = 0; r < 5; r++) {
        int o = obase + r;
        vv[r] = (o < lim);
        int j = j0 + (vv[r] ? o : 0);
        int k   = (j >= HW) + (j >= 2 * HW);
        int pix = j - k * HW;
        int qq  = pix >> sh;
        int py  = (qq * 9363) >> 16;   // exact /7 for qq<=448
        int px  = pix - py * W;
        float w  = (2.0f + 0.5f * (float)k) * stf;   // exact f32
        float cx = ((float)px + 0.5f) * stf;
        float cy = ((float)py + 0.5f) * stf;
        ax[r] = cx - 0.5f * w; ay[r] = cy - 0.5f * w;
        az[r] = cx + 0.5f * w; aw[r] = cy + 0.5f * w;
        ar[r] = w * w;
        bn[r] = 0.f; bu[r] = 1.f; at_[r] = 0;   // represents iou==0, argmax t=0
        kk[r] = k; pp[r] = pix;
        xlo = fminf(xlo, ax[r]); xhi = fmaxf(xhi, az[r]);
        ylo = fminf(ylo, ay[r]); yhi = fmaxf(yhi, aw[r]);
    }

    for (int t = 0; t < T; t++) {
        float4 g = s_box[t];
        // disjoint-from-band => IoU is exactly 0 for all 5 anchors => skip
        if (g.x < xhi && g.z > xlo && g.y < yhi && g.w > ylo) {
            float ab = s_ab[t];
#pragma unroll
            for (int r = 0; r < 5; r++) {
                float lx = fmaxf(ax[r], g.x), ly = fmaxf(ay[r], g.y);
                float rx = fminf(az[r], g.z), ry = fminf(aw[r], g.w);
                float ww = fmaxf(rx - lx, 0.f), hh = fmaxf(ry - ly, 0.f);
                float inter = ww * hh;
                float u = ((ar[r] + ab) - inter) + 1e-9f;
                if (inter * bu[r] > bn[r] * u) { bn[r] = inter; bu[r] = u; at_[r] = t; }
            }
        }
    }

    const float* objbase = pred + (size_t)(b * 24 + 4) * HW;
    const unsigned base = (unsigned)(b * APB + ((s == 0) ? 0 : (s == 1) ? 9408 : 11760));
    unsigned npnn = 0;
#pragma unroll
    for (int r = 0; r < 5; r++) {
        if (vv[r]) {
            int j = j0 + obase + r;
            bool pos = (bn[r] + bn[r] >= bu[r]);   // max_iou >= 0.5
            bool neg = (bn[r] < 0.3f * bu[r]);     // max_iou <  0.3
            unsigned key = 0u;
            if (neg) key = mapf(objbase[(size_t)kk[r] * 8 * HW + pp[r]]);
            wsu[KEY_OFF + base + j] = key;
            mf[base + j] = (unsigned short)(at_[r] | (pos ? 0x100 : 0) | (neg ? 0x200 : 0));
            npnn += (pos ? 1u : 0u) + (neg ? 0x10000u : 0u);
        }
    }
    for (int off = 32; off; off >>= 1) npnn += (unsigned)__shfl_down((int)npnn, off, 64);
    if (lane == 0) s_np[wid] = npnn;
    __syncthreads();
    if (tid == 0) wsu[NPNN_OFF + blk] = s_np[0] + s_np[1] + s_np[2] + s_np[3];
}

// ---------------------------------------------------------------------------
// K2: per-(b,s) forced positives + radix-select hard-neg mining + losses.
// ---------------------------------------------------------------------------
__global__ __launch_bounds__(1024) void select_loss_kernel(
    const float* __restrict__ pred1, const float* __restrict__ pred2,
    const float* __restrict__ pred3, const float* __restrict__ tboxes,
    const int* __restrict__ tlabels,
    unsigned* __restrict__ wsu, unsigned short* __restrict__ mf)
{
#pragma clang fp contract(off)
    const int bid = blockIdx.x;
    const int b = bid / 3, s = bid - 3 * b;
    const float* __restrict__ pred = (s == 0) ? pred1 : (s == 1) ? pred2 : pred3;
    const int W = 56 >> s, HW = W * W, A = 3 * HW;
    const float stf = (float)(8 << s);
    const int sh = 3 - s;
    const unsigned base = (unsigned)(b * APB + ((s == 0) ? 0 : (s == 1) ? 9408 : 11760));

    __shared__ float4   s_box[T];
    __shared__ int      s_lab[T];
    __shared__ int      s_besta[T];
    __shared__ unsigned s_misc[4];   // [0]=npnn adjust  [1],[2]=radix/npnn bcast
    __shared__ float    s_redf[16 * 4];
    __shared__ unsigned hist[2048];

    const int tid = threadIdx.x, lane = tid & 63, wid = tid >> 6;

    if (tid < T) {
        s_box[tid] = ((const float4*)tboxes)[b * T + tid];
        s_lab[tid] = tlabels[b * T + tid];
    }
    if (tid >= 32 && tid < 36) s_misc[tid - 32] = 0;
    __syncthreads();

    // ---- windowed per-box best anchor (one wave per box) -------------------
    for (int t = wid; t < T; t += 16) {
        float4 g = s_box[t];
        float  ab = (g.z - g.x) * (g.w - g.y);
        int px0 = max(0, (int)floorf(g.x / stf) - 2);
        int px1 = min(W - 1, (int)floorf(g.z / stf) + 2);
        int py0 = max(0, (int)floorf(g.y / stf) - 2);
        int py1 = min(W - 1, (int)floorf(g.w / stf) + 2);
        int rowlen = (px1 - px0 + 1) * 3;
        float bi = -1.f, bu2 = 1.f;
        int ba = 0;
        for (int py = py0; py <= py1; py++) {
            float cy = ((float)py + 0.5f) * stf;
            for (int cc = lane; cc < rowlen; cc += 64) {
                int ix = (cc * 21846) >> 16;
                int k  = cc - 3 * ix;
                int px = px0 + ix;
                float w  = (2.0f + 0.5f * (float)k) * stf;
                float cx = ((float)px + 0.5f) * stf;
                float lx = fmaxf(cx - 0.5f * w, g.x), ly = fmaxf(cy - 0.5f * w, g.y);
                float rx = fminf(cx + 0.5f * w, g.z), ry = fminf(cy + 0.5f * w, g.w);
                float ww = fmaxf(rx - lx, 0.f), hh = fmaxf(ry - ly, 0.f);
                float inter = ww * hh;
                float u = ((w * w + ab) - inter) + 1e-9f;
                if (inter * bu2 > bi * u) {
                    bi = inter; bu2 = u; ba = (py * W + px) * 3 + k;
                }
            }
        }
        for (int off = 32; off; off >>= 1) {
            float oi = __shfl_down(bi, off, 64);
            float ou = __shfl_down(bu2, off, 64);
            int   oa = __shfl_down(ba, off, 64);
            float l = oi * bu2, r = bi * ou;
            if (l > r || (l == r && oa < ba)) { bi = oi; bu2 = ou; ba = oa; }
        }
        if (lane == 0) s_besta[t] = ba;
    }
    __syncthreads();

    // ---- apply overrides (winner=last t; first-occurrence adjusts counts) --
    int  j20 = 0; bool winner = false;
    if (tid < T) {
        int a = s_besta[tid];
        winner = true; bool first = true;
        for (int t2 = tid + 1; t2 < T; t2++) if (s_besta[t2] == a) winner = false;
        for (int t2 = 0; t2 < tid; t2++)     if (s_besta[t2] == a) first  = false;
        int pix = (a * 21846) >> 16;
        int k = a - 3 * pix;
        j20 = k * HW + pix;
        if (first) {
            unsigned old = mf[base + j20];
            unsigned d = ((old & 0x100u) ? 0u : 1u) +
                         ((old & 0x200u) ? 0xFFFF0000u : 0u);  // nn -= 1
            atomicAdd(&s_misc[0], d);
        }
    }
    __syncthreads();
    if (tid < T && winner) {
        mf[base + j20] = (unsigned short)(tid | 0x100);
        wsu[KEY_OFF + base + j20] = 0u;
    }
    __threadfence_block();
    __syncthreads();

    // ---- np/nn from per-match-block slots ----------------------------------
    if (tid == 0) {
        int nslots = (s == 0) ? 8 : (s == 1) ? 2 : 1;
        int sb = b * 11 + ((s == 0) ? 0 : (s == 1) ? 8 : 10);
        unsigned p = 0;
        for (int i = 0; i < nslots; i++) p += wsu[NPNN_OFF + sb + i];
        s_misc[1] = p;
    }
    __syncthreads();
    unsigned packed = s_misc[1] + s_misc[0];
    unsigned np = packed & 0xFFFFu, nn = packed >> 16;
    unsigned need = min(3u * np, nn);

    // ---- load keys + flags to registers (after overrides) ------------------
    unsigned keyreg[10];
    unsigned short mfr[10];
#pragma unroll
    for (int m = 0; m < 10; m++) {
        int j = tid + m * 1024;
        keyreg[m] = (j < A) ? wsu[KEY_OFF + base + j] : 0u;
        mfr[m]    = (j < A) ? mf[base + j] : (unsigned short)0;
    }

    // ---- exact k-th largest neg key: 3-pass radix select (11/11/10 bits) ---
    unsigned kth = 0xFFFFFFFFu;
    if (need > 0) {
        unsigned prefix = 0, remaining = need;
        const int shifts[3] = {21, 10, 0};
        const int nbits[3]  = {11, 11, 10};
        for (int p = 0; p < 3; p++) {
            const int NB = 1 << nbits[p];
            const int sh_ = shifts[p];
            for (int i = tid; i < NB; i += 1024) hist[i] = 0;
            __syncthreads();
#pragma unroll
            for (int m = 0; m < 10; m++) {
                unsigned k = keyreg[m];
                bool ok = (p == 0) || ((k >> (sh_ + nbits[p])) == prefix);
                if (ok) atomicAdd(&hist[(k >> sh_) & (NB - 1)], 1u);
            }
            __syncthreads();
            if (wid == 0) {
                const int C = NB >> 6;
                int b0 = lane * C;
                unsigned csum = 0;
                for (int i = 0; i < C; i++) csum += hist[b0 + i];
                unsigned Tv = csum;
                for (int off = 1; off < 64; off <<= 1) {
                    unsigned o = __shfl_down(Tv, off, 64);
                    if (lane + off < 64) Tv += o;
                }
                // Tv = suffix sum over lanes >= lane (decreasing in lane)
                unsigned long long ball = __ballot(Tv >= remaining);
                int L = 63 - __clzll(ball);
                if (lane == L) {
                    unsigned sv = Tv - csum;   // count above this chunk
                    int bb = b0 + C - 1;
                    while (true) { sv += hist[bb]; if (sv >= remaining) break; bb--; }
                    s_misc[1] = (unsigned)bb;
                    s_misc[2] = sv - hist[bb];  // count strictly above bin bb
                }
            }
            __syncthreads();
            unsigned B = s_misc[1];
            remaining -= s_misc[2];
            prefix = (prefix << nbits[p]) | B;
        }
        kth = prefix;
    }

    // ---- losses ------------------------------------------------------------
    float obj_s = 0.f, cls_s = 0.f, loc_s = 0.f;
    unsigned cgt = 0;
#pragma unroll 1
    for (int m = 0; m < 10; m++) {
        int j = tid + m * 1024;
        if (j >= A) break;
        unsigned mfv = mfr[m];
        if (mfv & 0x100u) {
            int k   = (j >= HW) + (j >= 2 * HW);
            int pix = j - k * HW;
            const float* bp = pred + (size_t)(b * 24 + k * 8) * HW + pix;
            float x = bp[(size_t)4 * HW];
            obj_s += bce_pos(x);
            int t = mfv & 0xFFu;
            float4 g = s_box[t];
            int tgt = s_lab[t] - 1;
            float c0 = bp[(size_t)5 * HW], c1 = bp[(size_t)6 * HW], c2 = bp[(size_t)7 * HW];
            float mm  = fmaxf(c0, fmaxf(c1, c2));
            float lse = logf(expf(c0 - mm) + expf(c1 - mm) + expf(c2 - mm));
            float ct = (tgt == 0) ? c0 : (tgt == 1) ? c1 : c2;
            cls_s += (mm + lse) - ct;
            int qq = pix >> sh;
            int py = (qq * 9363) >> 16;
            int px = pix - py * W;
            float w  = (2.0f + 0.5f * (float)k) * stf;
            float cx = ((float)px + 0.5f) * stf;
            float cy = ((float)py + 0.5f) * stf;
            float gcx = (g.x + g.z) * 0.5f, gcy = (g.y + g.w) * 0.5f;
            float gw = g.z - g.x, gh = g.w - g.y;
            float t0 = (gcx - cx) / w, t1 = (gcy - cy) / w;
            float t2 = logf(gw / w),   t3 = logf(gh / w);
            float d0 = bp[0], d1 = bp[(size_t)HW], d2 = bp[(size_t)2 * HW], d3 = bp[(size_t)3 * HW];
            float dd;
            dd = fabsf(d0 - t0); loc_s += (dd < 1.f) ? 0.5f * dd * dd : dd - 0.5f;
            dd = fabsf(d1 - t1); loc_s += (dd < 1.f) ? 0.5f * dd * dd : dd - 0.5f;
            dd = fabsf(d2 - t2); loc_s += (dd < 1.f) ? 0.5f * dd * dd : dd - 0.5f;
            dd = fabsf(d3 - t3); loc_s += (dd < 1.f) ? 0.5f * dd * dd : dd - 0.5f;
        } else {
            unsigned key = keyreg[m];
            if (key > kth) { obj_s += bce_neg(unmapf(key)); cgt++; }
        }
    }
    for (int off = 32; off; off >>= 1) {
        obj_s += __shfl_down(obj_s, off, 64);
        cls_s += __shfl_down(cls_s, off, 64);
        loc_s += __shfl_down(loc_s, off, 64);
        cgt   += (unsigned)__shfl_down((int)cgt, off, 64);
    }
    if (lane == 0) {
        s_redf[wid * 4 + 0] = obj_s;
        s_redf[wid * 4 + 1] = cls_s;
        s_redf[wid * 4 + 2] = loc_s;
        s_redf[wid * 4 + 3] = __uint_as_float(cgt);
    }
    __syncthreads();
    if (tid == 0) {
        float ob = 0.f, cl = 0.f, lc = 0.f;
        unsigned cg = 0;
        for (int w2 = 0; w2 < 16; w2++) {
            ob += s_redf[w2 * 4 + 0];
            cl += s_redf[w2 * 4 + 1];
            lc += s_redf[w2 * 4 + 2];
            cg += __float_as_uint(s_redf[w2 * 4 + 3]);
        }
        if (need > 0) ob += (float)(need - cg) * bce_neg(unmapf(kth));
        float* wsf = (float*)wsu;
        wsf[LOSS_OFF + bid * 3 + 0] = ob / (float)max(np + need, 1u);
        wsf[LOSS_OFF + bid * 3 + 1] = cl / (float)max(np, 1u);
        wsf[LOSS_OFF + bid * 3 + 2] = lc / (float)max(4u * np, 1u);
    }
}

__global__ void finalize_kernel(const float* __restrict__ wsf,
                                float* __restrict__ out) {
    const int t = threadIdx.x, lane = t & 63, wid = t >> 6;
    __shared__ float red[12];
    float v0 = 0.f, v1 = 0.f, v2 = 0.f;
    if (t < 192) {
        v0 = wsf[LOSS_OFF + 3 * t];
        v1 = wsf[LOSS_OFF + 3 * t + 1];
        v2 = wsf[LOSS_OFF + 3 * t + 2];
    }
    for (int off = 32; off; off >>= 1) {
        v0 += __shfl_down(v0, off, 64);
        v1 += __shfl_down(v1, off, 64);
        v2 += __shfl_down(v2, off, 64);
    }
    if (lane == 0) { red[wid * 3] = v0; red[wid * 3 + 1] = v1; red[wid * 3 + 2] = v2; }
    __syncthreads();
    if (t == 0) {
        float obj = 0.f, cls = 0.f, loc = 0.f;
        for (int w2 = 0; w2 < 4; w2++) {
            obj += red[w2 * 3]; cls += red[w2 * 3 + 1]; loc += red[w2 * 3 + 2];
        }
        obj /= 64.f; cls /= 64.f; loc /= 64.f;
        out[0] = obj; out[1] = cls; out[2] = loc;
        out[3] = obj + cls + 2.f * loc;
    }
}

extern "C" void kernel_launch(void* const* d_in, const int* in_sizes, int n_in,
                              void* d_out, int out_size, void* d_ws, size_t ws_size,
                              hipStream_t stream) {
    const float* pred1   = (const float*)d_in[0];
    const float* pred2   = (const float*)d_in[1];
    const float* pred3   = (const float*)d_in[2];
    const float* tboxes  = (const float*)d_in[6];
    const int*   tlabels = (const int*)d_in[7];
    unsigned* wsu = (unsigned*)d_ws;
    unsigned short* mf = (unsigned short*)((char*)d_ws + MF_BYTE_OFF);
    float* out = (float*)d_out;

    match_kernel<<<64 * 11, 256, 0, stream>>>(pred1, pred2, pred3, tboxes, wsu, mf);
    select_loss_kernel<<<64 * 3, 1024, 0, stream>>>(
        pred1, pred2, pred3, tboxes, tlabels, wsu, mf);
    finalize_kernel<<<1, 256, 0, stream>>>((const float*)d_ws, out);
}

// Round 5
// 120.696 us; speedup vs baseline: 2.4855x; 1.0302x over previous
//
#include <hip/hip_runtime.h>
#include <math.h>

#define T 20
#define LOSS_OFF 16          // float index into ws: 192*3 per-(b,s) loss triples

static __device__ __forceinline__ unsigned mapf(float x) {
    unsigned u = __float_as_uint(x);
    return (u & 0x80000000u) ? ~u : (u | 0x80000000u);
}
static __device__ __forceinline__ float unmapf(unsigned m) {
    return __uint_as_float((m & 0x80000000u) ? (m ^ 0x80000000u) : ~m);
}
static __device__ __forceinline__ float bce_pos(float x) {
    return fmaxf(x, 0.f) - x + log1pf(expf(-fabsf(x)));
}
static __device__ __forceinline__ float bce_neg(float x) {
    return fmaxf(x, 0.f) + log1pf(expf(-fabsf(x)));
}

// ---------------------------------------------------------------------------
// Fused per-(b,s) kernel: match (registers) + forced positives + radix-select
// hard-negative mining + losses. 192 blocks x 1024. Keys never touch global.
// ---------------------------------------------------------------------------
__global__ __launch_bounds__(1024, 1) void fused_kernel(
    const float* __restrict__ pred1, const float* __restrict__ pred2,
    const float* __restrict__ pred3, const float* __restrict__ tboxes,
    const int* __restrict__ tlabels, float* __restrict__ wsf)
{
#pragma clang fp contract(off)
    const int bid = blockIdx.x;
    const int b = bid / 3, s = bid - 3 * b;
    const float* __restrict__ pred = (s == 0) ? pred1 : (s == 1) ? pred2 : pred3;
    const int W = 56 >> s, HW = W * W, A = 3 * HW;
    const float stf = (float)(8 << s);
    const int sh = 3 - s;

    __shared__ float4   s_box[T];
    __shared__ float    s_ab[T];
    __shared__ int      s_lab[T];
    __shared__ int      s_besta[T];
    __shared__ unsigned s_npnn;
    __shared__ unsigned s_bc[2];
    __shared__ float    s_redf[16 * 4];
    __shared__ unsigned hist[2048];

    const int tid = threadIdx.x, lane = tid & 63, wid = tid >> 6;

    if (tid < T) {
        float4 g = ((const float4*)tboxes)[b * T + tid];
        s_box[tid] = g;
        s_ab[tid]  = (g.z - g.x) * (g.w - g.y);
        s_lab[tid] = tlabels[b * T + tid];
    }
    if (tid == 0) s_npnn = 0u;
    __syncthreads();

    const float* objbase = pred + (size_t)(b * 24 + 4) * HW;

    // ---- match phase: 2 batches x 5 contiguous anchors, all in registers ---
    unsigned keyreg[10];
    unsigned mfr[10];
#pragma unroll
    for (int m = 0; m < 10; m++) { keyreg[m] = 0u; mfr[m] = 0u; }

#pragma unroll
    for (int bat = 0; bat < 2; bat++) {
        int jb = bat * 5120 + 5 * tid;
        if (jb < A) {
            float ax[5], ay[5], az[5], aw[5], ar[5], bn[5], bu[5];
            int at_[5];
            float xlo = 1e30f, xhi = -1e30f, ylo = 1e30f, yhi = -1e30f;
#pragma unroll
            for (int r = 0; r < 5; r++) {
                int j = jb + r; if (j >= A) j = A - 1;  // clamp for coords only
                int k   = (j >= HW) + (j >= 2 * HW);
                int pix = j - k * HW;
                int qq  = pix >> sh;
                int py  = (qq * 9363) >> 16;   // exact /7 for qq<=448
                int px  = pix - py * W;
                float w  = (2.0f + 0.5f * (float)k) * stf;   // exact f32
                float cx = ((float)px + 0.5f) * stf;
                float cy = ((float)py + 0.5f) * stf;
                ax[r] = cx - 0.5f * w; ay[r] = cy - 0.5f * w;
                az[r] = cx + 0.5f * w; aw[r] = cy + 0.5f * w;
                ar[r] = w * w;
                bn[r] = 0.f; bu[r] = 1.f; at_[r] = 0;  // iou==0 -> argmax t=0
                xlo = fminf(xlo, ax[r]); xhi = fmaxf(xhi, az[r]);
                ylo = fminf(ylo, ay[r]); yhi = fmaxf(yhi, aw[r]);
            }
            for (int t = 0; t < T; t++) {
                float4 g = s_box[t];
                // disjoint from the 5-anchor band => IoU exactly 0 => skip
                if (g.x < xhi && g.z > xlo && g.y < yhi && g.w > ylo) {
                    float ab = s_ab[t];
#pragma unroll
                    for (int r = 0; r < 5; r++) {
                        float lx = fmaxf(ax[r], g.x), ly = fmaxf(ay[r], g.y);
                        float rx = fminf(az[r], g.z), ry = fminf(aw[r], g.w);
                        float ww = fmaxf(rx - lx, 0.f), hh = fmaxf(ry - ly, 0.f);
                        float inter = ww * hh;
                        float u = ((ar[r] + ab) - inter) + 1e-9f;
                        if (inter * bu[r] > bn[r] * u) {
                            bn[r] = inter; bu[r] = u; at_[r] = t;
                        }
                    }
                }
            }
#pragma unroll
            for (int r = 0; r < 5; r++) {
                int j = jb + r;
                if (j < A) {
                    int k   = (j >= HW) + (j >= 2 * HW);
                    int pix = j - k * HW;
                    bool pos = (bn[r] + bn[r] >= bu[r]);   // max_iou >= 0.5
                    bool neg = (bn[r] < 0.3f * bu[r]);     // max_iou <  0.3
                    unsigned key = 0u;
                    if (neg) key = mapf(objbase[(size_t)k * 8 * HW + pix]);
                    keyreg[bat * 5 + r] = key;
                    mfr[bat * 5 + r] = (unsigned)at_[r] | (pos ? 0x100u : 0u)
                                                        | (neg ? 0x200u : 0u);
                }
            }
        }
    }

    // ---- windowed per-box best anchor (one wave per box) -------------------
    for (int t = wid; t < T; t += 16) {
        float4 g = s_box[t];
        float  ab = s_ab[t];
        int px0 = max(0, (int)floorf(g.x / stf) - 2);
        int px1 = min(W - 1, (int)floorf(g.z / stf) + 2);
        int py0 = max(0, (int)floorf(g.y / stf) - 2);
        int py1 = min(W - 1, (int)floorf(g.w / stf) + 2);
        int rowlen = (px1 - px0 + 1) * 3;
        float bi = -1.f, bu2 = 1.f;
        int ba = 0;
        for (int py = py0; py <= py1; py++) {
            float cy = ((float)py + 0.5f) * stf;
            for (int cc = lane; cc < rowlen; cc += 64) {
                int ix = (cc * 21846) >> 16;   // /3
                int k  = cc - 3 * ix;
                int px = px0 + ix;
                float w  = (2.0f + 0.5f * (float)k) * stf;
                float cx = ((float)px + 0.5f) * stf;
                float lx = fmaxf(cx - 0.5f * w, g.x), ly = fmaxf(cy - 0.5f * w, g.y);
                float rx = fminf(cx + 0.5f * w, g.z), ry = fminf(cy + 0.5f * w, g.w);
                float ww = fmaxf(rx - lx, 0.f), hh = fmaxf(ry - ly, 0.f);
                float inter = ww * hh;
                float u = ((w * w + ab) - inter) + 1e-9f;
                if (inter * bu2 > bi * u) {
                    bi = inter; bu2 = u; ba = (py * W + px) * 3 + k;
                }
            }
        }
        for (int off = 32; off; off >>= 1) {
            float oi = __shfl_down(bi, off, 64);
            float ou = __shfl_down(bu2, off, 64);
            int   oa = __shfl_down(ba, off, 64);
            float l = oi * bu2, r = bi * ou;
            if (l > r || (l == r && oa < ba)) { bi = oi; bu2 = ou; ba = oa; }
        }
        if (lane == 0) {
            // anchor index (pix,k) -> flattened j = k*HW + pix
            int pix = (ba * 21846) >> 16;
            int k = ba - 3 * pix;
            s_besta[t] = k * HW + pix;
        }
    }
    __syncthreads();

    // ---- forced-positive overrides in registers (last t wins) --------------
    {
        int best[T];
#pragma unroll
        for (int t = 0; t < T; t++) best[t] = s_besta[t];
#pragma unroll
        for (int m = 0; m < 10; m++) {
            int j = (m / 5) * 5120 + 5 * tid + (m - (m / 5) * 5);
            int twin = -1;
#pragma unroll
            for (int t = 0; t < T; t++) if (best[t] == j) twin = t;  // last wins
            if (twin >= 0) { mfr[m] = (unsigned)twin | 0x100u; keyreg[m] = 0u; }
        }
    }

    // ---- np/nn counted post-override (exact, no adjustment) ----------------
    unsigned npnn = 0;
#pragma unroll
    for (int m = 0; m < 10; m++)
        npnn += ((mfr[m] >> 8) & 1u) + (((mfr[m] >> 9) & 1u) << 16);
    for (int off = 32; off; off >>= 1) npnn += (unsigned)__shfl_down((int)npnn, off, 64);
    if (lane == 0) atomicAdd(&s_npnn, npnn);
    __syncthreads();
    unsigned packed = s_npnn;
    unsigned np = packed & 0xFFFFu, nn = packed >> 16;
    unsigned need = min(3u * np, nn);

    // ---- exact k-th largest neg key: 3-pass radix select (11/11/10 bits) ---
    unsigned kth = 0xFFFFFFFFu;
    if (need > 0) {
        unsigned prefix = 0, remaining = need;
        const int shifts[3] = {21, 10, 0};
        const int nbits[3]  = {11, 11, 10};
        for (int p = 0; p < 3; p++) {
            const int NB = 1 << nbits[p];
            const int sh_ = shifts[p];
            for (int i = tid; i < NB; i += 1024) hist[i] = 0;
            __syncthreads();
#pragma unroll
            for (int m = 0; m < 10; m++) {
                unsigned k = keyreg[m];
                bool ok = (p == 0) || ((k >> (sh_ + nbits[p])) == prefix);
                if (ok) atomicAdd(&hist[(k >> sh_) & (NB - 1)], 1u);
            }
            __syncthreads();
            if (wid == 0) {
                const int C = NB >> 6;
                int b0 = lane * C;
                unsigned csum = 0;
                for (int i = 0; i < C; i++) csum += hist[b0 + i];
                unsigned Tv = csum;
                for (int off = 1; off < 64; off <<= 1) {
                    unsigned o = __shfl_down(Tv, off, 64);
                    if (lane + off < 64) Tv += o;
                }
                unsigned long long ball = __ballot(Tv >= remaining);
                int L = 63 - __clzll(ball);
                if (lane == L) {
                    unsigned sv = Tv - csum;
                    int bb = b0 + C - 1;
                    while (true) { sv += hist[bb]; if (sv >= remaining) break; bb--; }
                    s_bc[0] = (unsigned)bb;
                    s_bc[1] = sv - hist[bb];
                }
            }
            __syncthreads();
            unsigned B = s_bc[0];
            remaining -= s_bc[1];
            prefix = (prefix << nbits[p]) | B;
        }
        kth = prefix;
    }

    // ---- losses ------------------------------------------------------------
    float obj_s = 0.f, cls_s = 0.f, loc_s = 0.f;
    unsigned cgt = 0;
#pragma unroll
    for (int m = 0; m < 10; m++) {
        int j = (m / 5) * 5120 + 5 * tid + (m - (m / 5) * 5);
        if (j < A) {
            unsigned mfv = mfr[m];
            if (mfv & 0x100u) {
                int k   = (j >= HW) + (j >= 2 * HW);
                int pix = j - k * HW;
                const float* bp = pred + (size_t)(b * 24 + k * 8) * HW + pix;
                float x = bp[(size_t)4 * HW];
                obj_s += bce_pos(x);
                int t = mfv & 0xFFu;
                float4 g = s_box[t];
                int tgt = s_lab[t] - 1;
                float c0 = bp[(size_t)5 * HW], c1 = bp[(size_t)6 * HW], c2 = bp[(size_t)7 * HW];
                float mm  = fmaxf(c0, fmaxf(c1, c2));
                float lse = logf(expf(c0 - mm) + expf(c1 - mm) + expf(c2 - mm));
                float ct = (tgt == 0) ? c0 : (tgt == 1) ? c1 : c2;
                cls_s += (mm + lse) - ct;
                int qq = pix >> sh;
                int py = (qq * 9363) >> 16;
                int px = pix - py * W;
                float w  = (2.0f + 0.5f * (float)k) * stf;
                float cx = ((float)px + 0.5f) * stf;
                float cy = ((float)py + 0.5f) * stf;
                float gcx = (g.x + g.z) * 0.5f, gcy = (g.y + g.w) * 0.5f;
                float gw = g.z - g.x, gh = g.w - g.y;
                float t0 = (gcx - cx) / w, t1 = (gcy - cy) / w;
                float t2 = logf(gw / w),   t3 = logf(gh / w);
                float d0 = bp[0], d1 = bp[(size_t)HW], d2 = bp[(size_t)2 * HW], d3 = bp[(size_t)3 * HW];
                float dd;
                dd = fabsf(d0 - t0); loc_s += (dd < 1.f) ? 0.5f * dd * dd : dd - 0.5f;
                dd = fabsf(d1 - t1); loc_s += (dd < 1.f) ? 0.5f * dd * dd : dd - 0.5f;
                dd = fabsf(d2 - t2); loc_s += (dd < 1.f) ? 0.5f * dd * dd : dd - 0.5f;
                dd = fabsf(d3 - t3); loc_s += (dd < 1.f) ? 0.5f * dd * dd : dd - 0.5f;
            } else {
                unsigned key = keyreg[m];
                if (key > kth) { obj_s += bce_neg(unmapf(key)); cgt++; }
            }
        }
    }
    for (int off = 32; off; off >>= 1) {
        obj_s += __shfl_down(obj_s, off, 64);
        cls_s += __shfl_down(cls_s, off, 64);
        loc_s += __shfl_down(loc_s, off, 64);
        cgt   += (unsigned)__shfl_down((int)cgt, off, 64);
    }
    if (lane == 0) {
        s_redf[wid * 4 + 0] = obj_s;
        s_redf[wid * 4 + 1] = cls_s;
        s_redf[wid * 4 + 2] = loc_s;
        s_redf[wid * 4 + 3] = __uint_as_float(cgt);
    }
    __syncthreads();
    if (tid == 0) {
        float ob = 0.f, cl = 0.f, lc = 0.f;
        unsigned cg = 0;
        for (int w2 = 0; w2 < 16; w2++) {
            ob += s_redf[w2 * 4 + 0];
            cl += s_redf[w2 * 4 + 1];
            lc += s_redf[w2 * 4 + 2];
            cg += __float_as_uint(s_redf[w2 * 4 + 3]);
        }
        if (need > 0) ob += (float)(need - cg) * bce_neg(unmapf(kth));
        wsf[LOSS_OFF + bid * 3 + 0] = ob / (float)max(np + need, 1u);
        wsf[LOSS_OFF + bid * 3 + 1] = cl / (float)max(np, 1u);
        wsf[LOSS_OFF + bid * 3 + 2] = lc / (float)max(4u * np, 1u);
    }
}

__global__ void finalize_kernel(const float* __restrict__ wsf,
                                float* __restrict__ out) {
    const int t = threadIdx.x, lane = t & 63, wid = t >> 6;
    __shared__ float red[12];
    float v0 = 0.f, v1 = 0.f, v2 = 0.f;
    if (t < 192) {
        v0 = wsf[LOSS_OFF + 3 * t];
        v1 = wsf[LOSS_OFF + 3 * t + 1];
        v2 = wsf[LOSS_OFF + 3 * t + 2];
    }
    for (int off = 32; off; off >>= 1) {
        v0 += __shfl_down(v0, off, 64);
        v1 += __shfl_down(v1, off, 64);
        v2 += __shfl_down(v2, off, 64);
    }
    if (lane == 0) { red[wid * 3] = v0; red[wid * 3 + 1] = v1; red[wid * 3 + 2] = v2; }
    __syncthreads();
    if (t == 0) {
        float obj = 0.f, cls = 0.f, loc = 0.f;
        for (int w2 = 0; w2 < 4; w2++) {
            obj += red[w2 * 3]; cls += red[w2 * 3 + 1]; loc += red[w2 * 3 + 2];
        }
        obj /= 64.f; cls /= 64.f; loc /= 64.f;
        out[0] = obj; out[1] = cls; out[2] = loc;
        out[3] = obj + cls + 2.f * loc;
    }
}

extern "C" void kernel_launch(void* const* d_in, const int* in_sizes, int n_in,
                              void* d_out, int out_size, void* d_ws, size_t ws_size,
                              hipStream_t stream) {
    const float* pred1   = (const float*)d_in[0];
    const float* pred2   = (const float*)d_in[1];
    const float* pred3   = (const float*)d_in[2];
    const float* tboxes  = (const float*)d_in[6];
    const int*   tlabels = (const int*)d_in[7];
    float* wsf = (float*)d_ws;
    float* out = (float*)d_out;

    fused_kernel<<<64 * 3, 1024, 0, stream>>>(
        pred1, pred2, pred3, tboxes, tlabels, wsf);
    finalize_kernel<<<1, 256, 0, stream>>>(wsf, out);
}